// Round 5
// baseline (6236.218 us; speedup 1.0000x reference)
//
#include <hip/hip_runtime.h>
#include <math.h>

// ---------------------------------------------------------------------------
// RNN_48558900248904: masked 2-layer alternating-parity tanh RNN, B=8192,
// T=200, H=256. Round 5: R4 + (1) amdgpu_waves_per_eu(2,2) -> 256-VGPR bin so
// the full-phase weight prefetch (2x16 frags = 128 VGPR) lives in registers
// (R4 capped at 128 VGPR and spilled); (2) t-loop unrolled x2 with
// compile-time parity (SGPR-folded weight bases, static h1 ping-pong);
// (3) s_setprio around MFMA chains; (4) raw exp2/rcp intrinsics.
// ---------------------------------------------------------------------------

typedef __attribute__((ext_vector_type(8))) short bf16x8;   // 8 bf16 (4 VGPRs)
typedef __attribute__((ext_vector_type(4))) short s16x4;    // 8B store
typedef __attribute__((ext_vector_type(4))) float f32x4;

#define MFMA(a, b, c) __builtin_amdgcn_mfma_f32_16x16x32_bf16((a), (b), (c), 0, 0, 0)

#define T_  200

// ws layout (units: shorts unless noted)
#define WLP_OFF   0                       // Wl packed: 16mt x 5kk x 64lane x 8e
#define WIHP_OFF  40960                   // 4 mats x 65536  ([l][p] flat)
#define WHHP_OFF  (40960 + 262144)
#define BSUM_BYTE_OFF ((40960 + 262144 + 262144) * 2)   // then [2][2][256] f32

// LDS layout (shorts)
#define XCS 168                           // xcat row stride (conflict-free)
#define HS  264                           // h/xproj row stride
#define SM_XCAT 0                         // [32][168] = 5376
#define SM_XPJ  5376                      // [32][264] = 8448 each
#define SM_H0   (SM_XPJ + 8448)
#define SM_H1A  (SM_H0 + 8448)
#define SM_H1B  (SM_H1A + 8448)
#define SM_BIAS (SM_H1B + 8448)          // 1280 f32 = 2560 shorts
#define SM_TOT  (SM_BIAS + 2560)         // 41984 shorts = 83968 B

__device__ __forceinline__ short f2bf(float f) {
    unsigned u = __float_as_uint(f);
    u += 0x7fffu + ((u >> 16) & 1u);      // RNE
    return (short)(u >> 16);
}
__device__ __forceinline__ float bf2f(short s) {
    return __uint_as_float(((unsigned)(unsigned short)s) << 16);
}
__device__ __forceinline__ float tanh_fast(float x) {
    float e = __builtin_amdgcn_exp2f(x * 2.88539008f);
    return 1.0f - 2.0f * __builtin_amdgcn_rcpf(e + 1.0f);
}

// ---------------------------------------------------------------------------
__global__ void prep_kernel(const float* __restrict__ Wl,
                            const float* __restrict__ Wih,
                            const float* __restrict__ Whh,
                            const float* __restrict__ bih,
                            const float* __restrict__ bhh,
                            short* __restrict__ wsS,
                            float* __restrict__ bsum) {
    int tid = blockIdx.x * 256 + threadIdx.x;
    if (tid < 5120) {                       // Wl pack (K padded 136 -> 160)
        int mt = tid / 320, rem = tid % 320;
        int kk = rem / 64, lane = rem % 64;
        int o = mt * 16 + (lane & 15);
        int kb = kk * 32 + (lane >> 4) * 8;
        short* dst = wsS + WLP_OFF + tid * 8;
#pragma unroll
        for (int e = 0; e < 8; e++) {
            int k = kb + e;
            dst[e] = f2bf((k < 136) ? Wl[o * 136 + k] : 0.0f);
        }
    } else if (tid < 5120 + 32768) {        // Wih pack
        int jj = tid - 5120;
        int mat = jj / 8192, rem = jj % 8192;
        int lane = rem & 63, kk = (rem >> 6) & 7, mt = rem >> 9;
        int o = mt * 16 + (lane & 15);
        int kb = kk * 32 + (lane >> 4) * 8;
        const float* src = Wih + (mat * 256 + o) * 256;
        short* dst = wsS + WIHP_OFF + mat * 65536 + rem * 8;
#pragma unroll
        for (int e = 0; e < 8; e++) dst[e] = f2bf(src[kb + e]);
    } else if (tid < 5120 + 65536) {        // Whh pack
        int jj = tid - 37888;
        int mat = jj / 8192, rem = jj % 8192;
        int lane = rem & 63, kk = (rem >> 6) & 7, mt = rem >> 9;
        int o = mt * 16 + (lane & 15);
        int kb = kk * 32 + (lane >> 4) * 8;
        const float* src = Whh + (mat * 256 + o) * 256;
        short* dst = wsS + WHHP_OFF + mat * 65536 + rem * 8;
#pragma unroll
        for (int e = 0; e < 8; e++) dst[e] = f2bf(src[kb + e]);
    } else if (tid < 5120 + 65536 + 1024) { // bsum = bih + bhh
        int j = tid - 70656;
        bsum[j] = bih[j] + bhh[j];
    }
}

// ---------------------------------------------------------------------------
struct GReg { f32x4 e0, e1, dv; };

__device__ __forceinline__ void gather_load(GReg& g, const float* __restrict__ dense,
                                            const int* __restrict__ sparse,
                                            const float* __restrict__ emb,
                                            int b0, int tt, int tid) {
    int gs = tid >> 4, gf = (tid >> 2) & 3, gq = tid & 3;
    int ix = sparse[(b0 + gs) * (T_ * 4) + tt * 4 + gf];
    const float* ep = emb + gf * 32000 + ix * 32 + gq * 8;
    g.e0 = *(const f32x4*)ep;
    g.e1 = *(const f32x4*)(ep + 4);
    if (tid < 64)
        g.dv = *(const f32x4*)(dense + (b0 + (tid >> 1)) * (T_ * 8) + tt * 8 + (tid & 1) * 4);
}
__device__ __forceinline__ void gather_commit(const GReg& g, short* __restrict__ buf, int tid) {
    int gs = tid >> 4, gf = (tid >> 2) & 3, gq = tid & 3;
    s16x4 w0, w1;
#pragma unroll
    for (int r = 0; r < 4; r++) { w0[r] = f2bf(g.e0[r]); w1[r] = f2bf(g.e1[r]); }
    int off = gs * XCS + 8 + gf * 32 + gq * 8;
    *(s16x4*)(buf + off) = w0;
    *(s16x4*)(buf + off + 4) = w1;
    if (tid < 64) {
        s16x4 wd;
#pragma unroll
        for (int r = 0; r < 4; r++) wd[r] = f2bf(g.dv[r]);
        *(s16x4*)(buf + (tid >> 1) * XCS + (tid & 1) * 4) = wd;
    }
}

// xproj = relu(Wl x xcat + bl) -> xpj   (wl prefetched into regs)
__device__ __forceinline__ void phaseA(const short* __restrict__ xcat,
                                       short* __restrict__ xpj,
                                       const short* __restrict__ wsS,
                                       const float* __restrict__ blS,
                                       int lane, int lrow, int lgrp, int wid) {
    bf16x8 wl[2][5];
#pragma unroll
    for (int kk = 0; kk < 5; kk++)
#pragma unroll
        for (int mt = 0; mt < 2; mt++)
            wl[mt][kk] = *(const bf16x8*)(wsS + WLP_OFF + (((wid * 2 + mt) * 5 + kk) * 64 + lane) * 8);
    f32x4 xacc[2][2];
#pragma unroll
    for (int mt = 0; mt < 2; mt++) {
        f32x4 bi = *(const f32x4*)(blS + wid * 32 + mt * 16 + lgrp * 4);
        xacc[mt][0] = bi; xacc[mt][1] = bi;
    }
#pragma unroll
    for (int kk = 0; kk < 5; kk++) {
        bf16x8 bxf[2];
#pragma unroll
        for (int nt = 0; nt < 2; nt++)
            bxf[nt] = *(const bf16x8*)(xcat + (nt * 16 + lrow) * XCS + kk * 32 + lgrp * 8);
#pragma unroll
        for (int mt = 0; mt < 2; mt++)
#pragma unroll
            for (int nt = 0; nt < 2; nt++) xacc[mt][nt] = MFMA(wl[mt][kk], bxf[nt], xacc[mt][nt]);
    }
#pragma unroll
    for (int mt = 0; mt < 2; mt++) {
        int o0 = wid * 32 + mt * 16 + lgrp * 4;
#pragma unroll
        for (int nt = 0; nt < 2; nt++) {
            s16x4 w;
#pragma unroll
            for (int r = 0; r < 4; r++) w[r] = f2bf(fmaxf(xacc[mt][nt][r], 0.0f));
            *(s16x4*)(xpj + (nt * 16 + lrow) * HS + o0) = w;
        }
    }
}

// ---------------------------------------------------------------------------
// One full RNN step (P = parity, compile-time). Two barriers.
template<int P>
__device__ __forceinline__ void rnn_step(
    int t, bool hasNext,
    const float* __restrict__ dense, const int* __restrict__ sparse,
    const float* __restrict__ emb, const short* __restrict__ wsS,
    const float* __restrict__ blS,
    short* __restrict__ xcat, short* __restrict__ xpj, short* __restrict__ h0p,
    short* __restrict__ h1a, short* __restrict__ h1b,
    bf16x8 (&hreg0)[2][8],
    int lane, int lrow, int lgrp, int wid, int len0, int len1, int b0, int tid)
{
    GReg g;
    if (hasNext) gather_load(g, dense, sparse, emb, b0, t + 1, tid);

    // ================= P1: layer0(t) =================
    {
        const short* Aih = wsS + WIHP_OFF + P * 65536;
        const short* Ahh = wsS + WHHP_OFF + P * 65536;
        bf16x8 wih[2][8], whh[2][8];     // full-phase weight prefetch
#pragma unroll
        for (int kk = 0; kk < 8; kk++)
#pragma unroll
            for (int mt = 0; mt < 2; mt++)
                wih[mt][kk] = *(const bf16x8*)(Aih + (((wid * 2 + mt) * 8 + kk) * 64 + lane) * 8);
#pragma unroll
        for (int kk = 0; kk < 8; kk++)
#pragma unroll
            for (int mt = 0; mt < 2; mt++)
                whh[mt][kk] = *(const bf16x8*)(Ahh + (((wid * 2 + mt) * 8 + kk) * 64 + lane) * 8);

        f32x4 acc[2][2];
#pragma unroll
        for (int mt = 0; mt < 2; mt++) {
            f32x4 bi = *(const f32x4*)(blS + 256 + P * 256 + wid * 32 + mt * 16 + lgrp * 4);
            acc[mt][0] = bi; acc[mt][1] = bi;
        }
        __builtin_amdgcn_s_setprio(1);
#pragma unroll
        for (int kk = 0; kk < 8; kk++) {       // ih: B from xpj (LDS)
            bf16x8 bf[2];
#pragma unroll
            for (int nt = 0; nt < 2; nt++)
                bf[nt] = *(const bf16x8*)(xpj + (nt * 16 + lrow) * HS + kk * 32 + lgrp * 8);
#pragma unroll
            for (int mt = 0; mt < 2; mt++)
#pragma unroll
                for (int nt = 0; nt < 2; nt++) acc[mt][nt] = MFMA(wih[mt][kk], bf[nt], acc[mt][nt]);
        }
#pragma unroll
        for (int kk = 0; kk < 8; kk++)         // hh: B from hreg0 (regs)
#pragma unroll
            for (int mt = 0; mt < 2; mt++)
#pragma unroll
                for (int nt = 0; nt < 2; nt++) acc[mt][nt] = MFMA(whh[mt][kk], hreg0[nt][kk], acc[mt][nt]);
        __builtin_amdgcn_s_setprio(0);

#pragma unroll
        for (int mt = 0; mt < 2; mt++) {       // in-place predicated write
            int o0 = wid * 32 + mt * 16 + lgrp * 4;
#pragma unroll
            for (int nt = 0; nt < 2; nt++) {
                s16x4 w;
#pragma unroll
                for (int r = 0; r < 4; r++) w[r] = f2bf(tanh_fast(acc[mt][nt][r]));
                int len = nt ? len1 : len0;
                if (t < len)
                    *(s16x4*)(h0p + (nt * 16 + lrow) * HS + o0) = w;
            }
        }
    }
    if (hasNext) gather_commit(g, xcat, tid);
    __syncthreads();   // h0 updated; xcat(t+1) committed

    // ================= P2: layer1(t) + xproj(t+1) =================
    {
        const short* h1r = P ? h1b : h1a;
        short* h1w = P ? h1a : h1b;
        const short* Aih = wsS + WIHP_OFF + (2 + P) * 65536;
        const short* Ahh = wsS + WHHP_OFF + (2 + P) * 65536;

        // fresh h0 B-frags: layer1 ih operand AND next P1's hh operand
#pragma unroll
        for (int nt = 0; nt < 2; nt++)
#pragma unroll
            for (int kk = 0; kk < 8; kk++)
                hreg0[nt][kk] = *(const bf16x8*)(h0p + (nt * 16 + lrow) * HS + kk * 32 + lgrp * 8);

        bf16x8 wih[2][8], whh[2][8];     // full-phase weight prefetch
#pragma unroll
        for (int kk = 0; kk < 8; kk++)
#pragma unroll
            for (int mt = 0; mt < 2; mt++)
                wih[mt][kk] = *(const bf16x8*)(Aih + (((wid * 2 + mt) * 8 + kk) * 64 + lane) * 8);
#pragma unroll
        for (int kk = 0; kk < 8; kk++)
#pragma unroll
            for (int mt = 0; mt < 2; mt++)
                whh[mt][kk] = *(const bf16x8*)(Ahh + (((wid * 2 + mt) * 8 + kk) * 64 + lane) * 8);

        f32x4 acc[2][2];
#pragma unroll
        for (int mt = 0; mt < 2; mt++) {
            f32x4 bi = *(const f32x4*)(blS + 256 + (2 + P) * 256 + wid * 32 + mt * 16 + lgrp * 4);
            acc[mt][0] = bi; acc[mt][1] = bi;
        }
        __builtin_amdgcn_s_setprio(1);
#pragma unroll
        for (int kk = 0; kk < 8; kk++)         // ih: B = hreg0
#pragma unroll
            for (int mt = 0; mt < 2; mt++)
#pragma unroll
                for (int nt = 0; nt < 2; nt++) acc[mt][nt] = MFMA(wih[mt][kk], hreg0[nt][kk], acc[mt][nt]);
#pragma unroll
        for (int kk = 0; kk < 8; kk++) {       // hh: B from h1r (LDS)
            bf16x8 bhf[2];
#pragma unroll
            for (int nt = 0; nt < 2; nt++)
                bhf[nt] = *(const bf16x8*)(h1r + (nt * 16 + lrow) * HS + kk * 32 + lgrp * 8);
#pragma unroll
            for (int mt = 0; mt < 2; mt++)
#pragma unroll
                for (int nt = 0; nt < 2; nt++) acc[mt][nt] = MFMA(whh[mt][kk], bhf[nt], acc[mt][nt]);
        }
        __builtin_amdgcn_s_setprio(0);

        if (hasNext)   // independent GEMM: interleaves with layer1 above
            phaseA(xcat, xpj, wsS, blS, lane, lrow, lgrp, wid);

        // h1 write: ping-pong with select-copy freeze
#pragma unroll
        for (int mt = 0; mt < 2; mt++) {
            int o0 = wid * 32 + mt * 16 + lgrp * 4;
#pragma unroll
            for (int nt = 0; nt < 2; nt++) {
                int roff = (nt * 16 + lrow) * HS + o0;
                s16x4 oldv = *(const s16x4*)(h1r + roff);
                s16x4 w;
#pragma unroll
                for (int r = 0; r < 4; r++) w[r] = f2bf(tanh_fast(acc[mt][nt][r]));
                int len = nt ? len1 : len0;
                *(s16x4*)(h1w + roff) = (t < len) ? w : oldv;
            }
        }
    }
    __syncthreads();   // h1(t), xpj(t+1) visible
}

// ---------------------------------------------------------------------------
__global__ __launch_bounds__(512)
__attribute__((amdgpu_waves_per_eu(2, 2))) void rnn_kernel(
    const float* __restrict__ dense, const int* __restrict__ sparse,
    const int* __restrict__ lengths, const float* __restrict__ emb,
    const float* __restrict__ bl, const float* __restrict__ Wout,
    const float* __restrict__ bout, const short* __restrict__ wsS,
    const float* __restrict__ bsum, float* __restrict__ out) {
    __shared__ alignas(16) short sm[SM_TOT];
    short* xcat = sm + SM_XCAT;
    short* xpj  = sm + SM_XPJ;
    short* h0p  = sm + SM_H0;
    short* h1a  = sm + SM_H1A;
    short* h1b  = sm + SM_H1B;
    float* blS  = (float*)(sm + SM_BIAS);   // [0,256)=bl, then bsum[q][256]

    const int tid  = threadIdx.x;
    const int wid  = tid >> 6;
    const int lane = tid & 63;
    const int lrow = lane & 15;
    const int lgrp = lane >> 4;
    const int b0   = blockIdx.x * 32;

    for (int i = tid; i < SM_BIAS; i += 512) sm[i] = 0;
    for (int i = tid; i < 1280; i += 512)
        blS[i] = (i < 256) ? bl[i] : bsum[i - 256];

    const int len0 = lengths[b0 + lrow];
    const int len1 = lengths[b0 + 16 + lrow];

    __syncthreads();
    { GReg g0; gather_load(g0, dense, sparse, emb, b0, 0, tid); gather_commit(g0, xcat, tid); }
    __syncthreads();
    phaseA(xcat, xpj, wsS, blS, lane, lrow, lgrp, wid);   // xproj(0)

    bf16x8 hreg0[2][8];            // B-frags of h0 (h0(-1) = 0)
#pragma unroll
    for (int nt = 0; nt < 2; nt++)
#pragma unroll
        for (int kk = 0; kk < 8; kk++) {
            bf16x8 z;
#pragma unroll
            for (int e = 0; e < 8; e++) z[e] = 0;
            hreg0[nt][kk] = z;
        }
    __syncthreads();               // xpj(0) visible

    for (int t = 0; t < T_; t += 2) {
        rnn_step<0>(t,     true,          dense, sparse, emb, wsS, blS,
                    xcat, xpj, h0p, h1a, h1b, hreg0,
                    lane, lrow, lgrp, wid, len0, len1, b0, tid);
        rnn_step<1>(t + 1, t + 1 < T_ - 1, dense, sparse, emb, wsS, blS,
                    xcat, xpj, h0p, h1a, h1b, hreg0,
                    lane, lrow, lgrp, wid, len0, len1, b0, tid);
    }

    // ---- epilogue: out = sigmoid(h1 . Wout + bout); final h1 = h1a (T even)
    float* red = (float*)(sm + SM_XPJ);
    if (tid < 256) {
        int s = tid >> 3, part = tid & 7;
        const short* hr = h1a + s * HS + part * 32;
        float sum = 0.0f;
#pragma unroll
        for (int k = 0; k < 32; k++) sum += bf2f(hr[k]) * Wout[part * 32 + k];
        red[s * 8 + part] = sum;
    }
    __syncthreads();
    if (tid < 32) {
        float x = bout[0];
#pragma unroll
        for (int i = 0; i < 8; i++) x += red[tid * 8 + i];
        float e = __builtin_amdgcn_exp2f(x * 1.44269504f);
        out[b0 + tid] = 1.0f - __builtin_amdgcn_rcpf(1.0f + e);
    }
}

// ---------------------------------------------------------------------------
extern "C" void kernel_launch(void* const* d_in, const int* in_sizes, int n_in,
                              void* d_out, int out_size, void* d_ws, size_t ws_size,
                              hipStream_t stream) {
    const float* dense   = (const float*)d_in[0];
    const int*   sparse  = (const int*)d_in[1];
    const int*   lengths = (const int*)d_in[2];
    const float* emb     = (const float*)d_in[3];
    const float* Wl      = (const float*)d_in[4];
    const float* bl      = (const float*)d_in[5];
    const float* Wih     = (const float*)d_in[6];
    const float* Whh     = (const float*)d_in[7];
    const float* bih     = (const float*)d_in[8];
    const float* bhh     = (const float*)d_in[9];
    const float* Wout    = (const float*)d_in[10];
    const float* bout    = (const float*)d_in[11];

    short* wsS  = (short*)d_ws;
    float* bsum = (float*)((char*)d_ws + BSUM_BYTE_OFF);

    prep_kernel<<<280, 256, 0, stream>>>(Wl, Wih, Whh, bih, bhh, wsS, bsum);
    rnn_kernel<<<256, 512, 0, stream>>>(dense, sparse, lengths, emb, bl, Wout, bout,
                                        wsS, bsum, (float*)d_out);
}

// Round 7
// 1375.030 us; speedup vs baseline: 4.5353x; 4.5353x over previous
//
#include <hip/hip_runtime.h>
#include <math.h>

// ---------------------------------------------------------------------------
// RNN_48558900248904. Round 7: R6 ring + TAIL-WAIT FIX.
// R6 raced on the tail chunk of every phase: at kk==7 the newest 4 VMEM ops
// are chunk 7's own DMAs, so vmcnt(4) could read slot 1 before the DMA
// landed (same at phaseA kk==4 / vmcnt(2)). Fix: position-exact waits —
// vmcnt(0) on the tail chunk only; all non-tail positions keep counted waits
// (wait count >= #newer ops => target chunk provably complete).
// ---------------------------------------------------------------------------

typedef __attribute__((ext_vector_type(8))) short bf16x8;   // 8 bf16 (4 VGPRs)
typedef __attribute__((ext_vector_type(4))) short s16x4;    // 8B store
typedef __attribute__((ext_vector_type(4))) float f32x4;

#define MFMA(a, b, c) __builtin_amdgcn_mfma_f32_16x16x32_bf16((a), (b), (c), 0, 0, 0)

#define T_  200

// ws layout (shorts)
#define WLP_OFF   0                       // Wl packed: ((mt*5+kk)*64+lane)*8
#define WIHP_OFF  40960                   // 4 mats x 65536: mat*65536+((mt*8+kk)*64+lane)*8
#define WHHP_OFF  (40960 + 262144)
#define BSUM_BYTE_OFF ((40960 + 262144 + 262144) * 2)   // then [2][2][256] f32

// LDS layout (shorts)
#define XCS 168
#define HS  264
#define SM_XCAT 0                         // [32][168] = 5376
#define SM_XPJ  5376                      // [32][264] = 8448 each
#define SM_H0   (SM_XPJ + 8448)
#define SM_H1A  (SM_H0 + 8448)
#define SM_H1B  (SM_H1A + 8448)
#define SM_BIAS (SM_H1B + 8448)          // 1280 f32 = 2560 shorts
#define SM_WRING (SM_BIAS + 2560)        // 8 waves x 4096 shorts (2 slots x 2048)
#define SM_TOT  (SM_WRING + 32768)       // 74496 shorts = 148992 B

__device__ __forceinline__ short f2bf(float f) {
    unsigned u = __float_as_uint(f);
    u += 0x7fffu + ((u >> 16) & 1u);      // RNE
    return (short)(u >> 16);
}
__device__ __forceinline__ float bf2f(short s) {
    return __uint_as_float(((unsigned)(unsigned short)s) << 16);
}
__device__ __forceinline__ float tanh_fast(float x) {
    float e = __builtin_amdgcn_exp2f(x * 2.88539008f);
    return 1.0f - 2.0f * __builtin_amdgcn_rcpf(e + 1.0f);
}

// global(16B per lane) -> LDS DMA (dest = uniform base + lane*16)
__device__ __forceinline__ void dma16(const short* g, short* l) {
    __builtin_amdgcn_global_load_lds(
        (const __attribute__((address_space(1))) void*)(unsigned long long)(g),
        (__attribute__((address_space(3))) void*)(unsigned int)(unsigned long long)(l),
        16, 0, 0);
}

#define VM_WAIT4() asm volatile("s_waitcnt vmcnt(4)" ::: "memory")
#define VM_WAIT2() asm volatile("s_waitcnt vmcnt(2)" ::: "memory")
#define VM_WAIT0() asm volatile("s_waitcnt vmcnt(0)" ::: "memory")
#define LGKM0()    asm volatile("s_waitcnt lgkmcnt(0)" ::: "memory")
#define BARRIER()  do { LGKM0(); __builtin_amdgcn_s_barrier(); \
                        __builtin_amdgcn_sched_barrier(0); } while (0)

// ---------------------------------------------------------------------------
__global__ void prep_kernel(const float* __restrict__ Wl,
                            const float* __restrict__ Wih,
                            const float* __restrict__ Whh,
                            const float* __restrict__ bih,
                            const float* __restrict__ bhh,
                            short* __restrict__ wsS,
                            float* __restrict__ bsum) {
    int tid = blockIdx.x * 256 + threadIdx.x;
    if (tid < 5120) {                       // Wl pack (K padded 136 -> 160)
        int mt = tid / 320, rem = tid % 320;
        int kk = rem / 64, lane = rem % 64;
        int o = mt * 16 + (lane & 15);
        int kb = kk * 32 + (lane >> 4) * 8;
        short* dst = wsS + WLP_OFF + tid * 8;
#pragma unroll
        for (int e = 0; e < 8; e++) {
            int k = kb + e;
            dst[e] = f2bf((k < 136) ? Wl[o * 136 + k] : 0.0f);
        }
    } else if (tid < 5120 + 32768) {        // Wih pack
        int jj = tid - 5120;
        int mat = jj / 8192, rem = jj % 8192;
        int lane = rem & 63, kk = (rem >> 6) & 7, mt = rem >> 9;
        int o = mt * 16 + (lane & 15);
        int kb = kk * 32 + (lane >> 4) * 8;
        const float* src = Wih + (mat * 256 + o) * 256;
        short* dst = wsS + WIHP_OFF + mat * 65536 + rem * 8;
#pragma unroll
        for (int e = 0; e < 8; e++) dst[e] = f2bf(src[kb + e]);
    } else if (tid < 5120 + 65536) {        // Whh pack
        int jj = tid - 37888;
        int mat = jj / 8192, rem = jj % 8192;
        int lane = rem & 63, kk = (rem >> 6) & 7, mt = rem >> 9;
        int o = mt * 16 + (lane & 15);
        int kb = kk * 32 + (lane >> 4) * 8;
        const float* src = Whh + (mat * 256 + o) * 256;
        short* dst = wsS + WHHP_OFF + mat * 65536 + rem * 8;
#pragma unroll
        for (int e = 0; e < 8; e++) dst[e] = f2bf(src[kb + e]);
    } else if (tid < 5120 + 65536 + 1024) { // bsum = bih + bhh
        int j = tid - 70656;
        bsum[j] = bih[j] + bhh[j];
    }
}

// ---------------------------------------------------------------------------
struct GReg { f32x4 e0, e1, dv; };

__device__ __forceinline__ void gather_load(GReg& g, const float* __restrict__ dense,
                                            const int* __restrict__ sparse,
                                            const float* __restrict__ emb,
                                            int b0, int tt, int tid) {
    int gs = tid >> 4, gf = (tid >> 2) & 3, gq = tid & 3;
    int ix = sparse[(b0 + gs) * (T_ * 4) + tt * 4 + gf];
    const float* ep = emb + gf * 32000 + ix * 32 + gq * 8;
    g.e0 = *(const f32x4*)ep;
    g.e1 = *(const f32x4*)(ep + 4);
    if (tid < 64)
        g.dv = *(const f32x4*)(dense + (b0 + (tid >> 1)) * (T_ * 8) + tt * 8 + (tid & 1) * 4);
}
__device__ __forceinline__ void gather_commit(const GReg& g, short* __restrict__ buf, int tid) {
    int gs = tid >> 4, gf = (tid >> 2) & 3, gq = tid & 3;
    s16x4 w0, w1;
#pragma unroll
    for (int r = 0; r < 4; r++) { w0[r] = f2bf(g.e0[r]); w1[r] = f2bf(g.e1[r]); }
    int off = gs * XCS + 8 + gf * 32 + gq * 8;
    *(s16x4*)(buf + off) = w0;
    *(s16x4*)(buf + off + 4) = w1;
    if (tid < 64) {
        s16x4 wd;
#pragma unroll
        for (int r = 0; r < 4; r++) wd[r] = f2bf(g.dv[r]);
        *(s16x4*)(buf + (tid >> 1) * XCS + (tid & 1) * 4) = wd;
    }
}

// chunk issues: 4-frag (ih mt0, ih mt1 | hh mt0, hh mt1) and 2-frag (Wl)
__device__ __forceinline__ void issue4(const short* Aih, const short* Ahh,
                                       short* slot, int wb, int kk, int lane) {
#pragma unroll
    for (int mt = 0; mt < 2; mt++) {
        dma16(Aih + (((wb + mt) * 8 + kk) * 64 + lane) * 8, slot + mt * 512);
        dma16(Ahh + (((wb + mt) * 8 + kk) * 64 + lane) * 8, slot + 1024 + mt * 512);
    }
}
__device__ __forceinline__ void issue2(const short* Wlp, short* slot, int wb, int kk, int lane) {
#pragma unroll
    for (int mt = 0; mt < 2; mt++)
        dma16(Wlp + (((wb + mt) * 5 + kk) * 64 + lane) * 8, slot + mt * 512);
}

// xproj = relu(Wl x xcat + bl); caller pre-issued w0,w1 into slots 0,1
__device__ __forceinline__ void phaseA_ring(short* __restrict__ xcat,
                                            short* __restrict__ xpj,
                                            const short* __restrict__ Wlp,
                                            const float* __restrict__ blS,
                                            short* ring,
                                            int lane, int lrow, int lgrp, int wid) {
    f32x4 xacc[2][2];
#pragma unroll
    for (int mt = 0; mt < 2; mt++) {
        f32x4 bi = *(const f32x4*)(blS + wid * 32 + mt * 16 + lgrp * 4);
        xacc[mt][0] = bi; xacc[mt][1] = bi;
    }
#pragma unroll
    for (int kk = 0; kk < 5; kk++) {
        short* slot = ring + (kk & 1) * 2048;
        if (kk == 4) { VM_WAIT0(); } else { VM_WAIT2(); }   // tail chunk: exact drain
        bf16x8 wl[2], bxf[2];
#pragma unroll
        for (int mt = 0; mt < 2; mt++)
            wl[mt] = *(const bf16x8*)(slot + mt * 512 + lane * 8);
#pragma unroll
        for (int nt = 0; nt < 2; nt++)
            bxf[nt] = *(const bf16x8*)(xcat + (nt * 16 + lrow) * XCS + kk * 32 + lgrp * 8);
#pragma unroll
        for (int mt = 0; mt < 2; mt++)
#pragma unroll
            for (int nt = 0; nt < 2; nt++) xacc[mt][nt] = MFMA(wl[mt], bxf[nt], xacc[mt][nt]);
        if (kk < 3) {
            LGKM0();
            issue2(Wlp, slot, wid * 2, kk + 2, lane);
        }
    }
#pragma unroll
    for (int mt = 0; mt < 2; mt++) {
        int o0 = wid * 32 + mt * 16 + lgrp * 4;
#pragma unroll
        for (int nt = 0; nt < 2; nt++) {
            s16x4 w;
#pragma unroll
            for (int r = 0; r < 4; r++) w[r] = f2bf(fmaxf(xacc[mt][nt][r], 0.0f));
            *(s16x4*)(xpj + (nt * 16 + lrow) * HS + o0) = w;
        }
    }
}

// ---------------------------------------------------------------------------
__global__ __launch_bounds__(512, 2) void rnn_kernel(
    const float* __restrict__ dense, const int* __restrict__ sparse,
    const int* __restrict__ lengths, const float* __restrict__ emb,
    const float* __restrict__ bl, const float* __restrict__ Wout,
    const float* __restrict__ bout, const short* __restrict__ wsS,
    const float* __restrict__ bsum, float* __restrict__ out) {
    __shared__ alignas(16) short sm[SM_TOT];
    short* xcat = sm + SM_XCAT;
    short* xpj  = sm + SM_XPJ;
    short* h0p  = sm + SM_H0;
    short* h1a  = sm + SM_H1A;
    short* h1b  = sm + SM_H1B;
    float* blS  = (float*)(sm + SM_BIAS);

    const int tid  = threadIdx.x;
    const int wid  = tid >> 6;
    const int lane = tid & 63;
    const int lrow = lane & 15;
    const int lgrp = lane >> 4;
    const int b0   = blockIdx.x * 32;
    short* ring = sm + SM_WRING + wid * 4096;
    const short* Wlp = wsS + WLP_OFF;

    for (int i = tid; i < SM_BIAS; i += 512) sm[i] = 0;
    for (int i = tid; i < 1280; i += 512)
        blS[i] = (i < 256) ? bl[i] : bsum[i - 256];

    const int len0 = lengths[b0 + lrow];
    const int len1 = lengths[b0 + 16 + lrow];

    __syncthreads();
    { GReg g0; gather_load(g0, dense, sparse, emb, b0, 0, tid); gather_commit(g0, xcat, tid); }
    __syncthreads();

    // initial xproj(0) via ring, then initial P1 prologue (p=0)
    issue2(Wlp, ring, wid * 2, 0, lane);
    issue2(Wlp, ring + 2048, wid * 2, 1, lane);
    phaseA_ring(xcat, xpj, Wlp, blS, ring, lane, lrow, lgrp, wid);
    LGKM0();
    issue4(wsS + WIHP_OFF, wsS + WHHP_OFF, ring,        wid * 2, 0, lane);
    issue4(wsS + WIHP_OFF, wsS + WHHP_OFF, ring + 2048, wid * 2, 1, lane);
    BARRIER();                      // xpj(0) visible; P1 chunks stay in flight

    bf16x8 hreg0[2][8];             // h0(-1) = 0
#pragma unroll
    for (int nt = 0; nt < 2; nt++)
#pragma unroll
        for (int kk = 0; kk < 8; kk++) {
            bf16x8 z;
#pragma unroll
            for (int e = 0; e < 8; e++) z[e] = 0;
            hreg0[nt][kk] = z;
        }

    f32x4 acc[2][2];

    for (int t = 0; t < T_; t++) {
        const int p = t & 1;
        const bool hasNext = (t + 1 < T_);
        const short* Aih1 = wsS + WIHP_OFF + p * 65536;
        const short* Ahh1 = wsS + WHHP_OFF + p * 65536;
        const short* Aih2 = wsS + WIHP_OFF + (2 + p) * 65536;
        const short* Ahh2 = wsS + WHHP_OFF + (2 + p) * 65536;

        GReg g;
        if (hasNext) gather_load(g, dense, sparse, emb, b0, t + 1, tid);

        // ================= P1: layer0(t) (chunks pre-issued) =================
#pragma unroll
        for (int mt = 0; mt < 2; mt++) {
            f32x4 bi = *(const f32x4*)(blS + 256 + p * 256 + wid * 32 + mt * 16 + lgrp * 4);
            acc[mt][0] = bi; acc[mt][1] = bi;
        }
#pragma unroll
        for (int kk = 0; kk < 8; kk++) {
            short* slot = ring + (kk & 1) * 2048;
            if (kk == 7) { VM_WAIT0(); } else { VM_WAIT4(); }   // tail: exact drain
            bf16x8 aih[2], ahh[2], bxf[2];
#pragma unroll
            for (int mt = 0; mt < 2; mt++) {
                aih[mt] = *(const bf16x8*)(slot + mt * 512 + lane * 8);
                ahh[mt] = *(const bf16x8*)(slot + 1024 + mt * 512 + lane * 8);
            }
#pragma unroll
            for (int nt = 0; nt < 2; nt++)
                bxf[nt] = *(const bf16x8*)(xpj + (nt * 16 + lrow) * HS + kk * 32 + lgrp * 8);
#pragma unroll
            for (int mt = 0; mt < 2; mt++)
#pragma unroll
                for (int nt = 0; nt < 2; nt++) {
                    acc[mt][nt] = MFMA(aih[mt], bxf[nt], acc[mt][nt]);
                    acc[mt][nt] = MFMA(ahh[mt], hreg0[nt][kk], acc[mt][nt]);
                }
            if (kk < 6) {
                LGKM0();
                issue4(Aih1, Ahh1, slot, wid * 2, kk + 2, lane);
            }
        }
#pragma unroll
        for (int mt = 0; mt < 2; mt++) {        // in-place predicated h0 write
            int o0 = wid * 32 + mt * 16 + lgrp * 4;
#pragma unroll
            for (int nt = 0; nt < 2; nt++) {
                s16x4 w;
#pragma unroll
                for (int r = 0; r < 4; r++) w[r] = f2bf(tanh_fast(acc[mt][nt][r]));
                int len = nt ? len1 : len0;
                if (t < len)
                    *(s16x4*)(h0p + (nt * 16 + lrow) * HS + o0) = w;
            }
        }
        LGKM0();                                // P1 slot reads done
        issue4(Aih2, Ahh2, ring,        wid * 2, 0, lane);   // P2 prologue
        issue4(Aih2, Ahh2, ring + 2048, wid * 2, 1, lane);
        if (hasNext) gather_commit(g, xcat, tid);
        BARRIER();   // h0(t), xcat(t+1) visible; P2 chunks in flight

        // ================= P2: layer1(t) =================
        const short* h1r = p ? h1b : h1a;
        short* h1w = p ? h1a : h1b;
#pragma unroll
        for (int mt = 0; mt < 2; mt++) {
            f32x4 bi = *(const f32x4*)(blS + 256 + (2 + p) * 256 + wid * 32 + mt * 16 + lgrp * 4);
            acc[mt][0] = bi; acc[mt][1] = bi;
        }
#pragma unroll
        for (int kk = 0; kk < 8; kk++) {
            short* slot = ring + (kk & 1) * 2048;
            if (kk == 7) { VM_WAIT0(); } else { VM_WAIT4(); }   // tail: exact drain
            bf16x8 aih[2], ahh[2], bhf[2];
#pragma unroll
            for (int mt = 0; mt < 2; mt++) {
                aih[mt] = *(const bf16x8*)(slot + mt * 512 + lane * 8);
                ahh[mt] = *(const bf16x8*)(slot + 1024 + mt * 512 + lane * 8);
            }
#pragma unroll
            for (int nt = 0; nt < 2; nt++) {    // fresh h0: ih operand + next P1 hh
                hreg0[nt][kk] = *(const bf16x8*)(h0p + (nt * 16 + lrow) * HS + kk * 32 + lgrp * 8);
                bhf[nt] = *(const bf16x8*)(h1r + (nt * 16 + lrow) * HS + kk * 32 + lgrp * 8);
            }
#pragma unroll
            for (int mt = 0; mt < 2; mt++)
#pragma unroll
                for (int nt = 0; nt < 2; nt++) {
                    acc[mt][nt] = MFMA(aih[mt], hreg0[nt][kk], acc[mt][nt]);
                    acc[mt][nt] = MFMA(ahh[mt], bhf[nt], acc[mt][nt]);
                }
            if (kk < 6) {
                LGKM0();
                issue4(Aih2, Ahh2, slot, wid * 2, kk + 2, lane);
            }
        }

        if (hasNext) {                           // xproj(t+1) via ring
            LGKM0();
            issue2(Wlp, ring, wid * 2, 0, lane);
            issue2(Wlp, ring + 2048, wid * 2, 1, lane);
            phaseA_ring(xcat, xpj, Wlp, blS, ring, lane, lrow, lgrp, wid);
        }

#pragma unroll
        for (int mt = 0; mt < 2; mt++) {         // h1 ping-pong select-freeze
            int o0 = wid * 32 + mt * 16 + lgrp * 4;
#pragma unroll
            for (int nt = 0; nt < 2; nt++) {
                int roff = (nt * 16 + lrow) * HS + o0;
                s16x4 oldv = *(const s16x4*)(h1r + roff);
                s16x4 w;
#pragma unroll
                for (int r = 0; r < 4; r++) w[r] = f2bf(tanh_fast(acc[mt][nt][r]));
                int len = nt ? len1 : len0;
                *(s16x4*)(h1w + roff) = (t < len) ? w : oldv;
            }
        }

        if (hasNext) {                           // next-step P1 prologue
            LGKM0();
            int pn = p ^ 1;
            issue4(wsS + WIHP_OFF + pn * 65536, wsS + WHHP_OFF + pn * 65536,
                   ring,        wid * 2, 0, lane);
            issue4(wsS + WIHP_OFF + pn * 65536, wsS + WHHP_OFF + pn * 65536,
                   ring + 2048, wid * 2, 1, lane);
        }
        BARRIER();   // h1(t), xpj(t+1) visible; next P1 chunks in flight
    }

    // ---- epilogue: out = sigmoid(h1 . Wout + bout); final h1 = h1a (T even)
    float* red = (float*)(sm + SM_XPJ);
    if (tid < 256) {
        int s = tid >> 3, part = tid & 7;
        const short* hr = h1a + s * HS + part * 32;
        float sum = 0.0f;
#pragma unroll
        for (int k = 0; k < 32; k++) sum += bf2f(hr[k]) * Wout[part * 32 + k];
        red[s * 8 + part] = sum;
    }
    __syncthreads();
    if (tid < 32) {
        float x = bout[0];
#pragma unroll
        for (int i = 0; i < 8; i++) x += red[tid * 8 + i];
        float e = __builtin_amdgcn_exp2f(x * 1.44269504f);
        out[b0 + tid] = 1.0f - __builtin_amdgcn_rcpf(1.0f + e);
    }
}

// ---------------------------------------------------------------------------
extern "C" void kernel_launch(void* const* d_in, const int* in_sizes, int n_in,
                              void* d_out, int out_size, void* d_ws, size_t ws_size,
                              hipStream_t stream) {
    const float* dense   = (const float*)d_in[0];
    const int*   sparse  = (const int*)d_in[1];
    const int*   lengths = (const int*)d_in[2];
    const float* emb     = (const float*)d_in[3];
    const float* Wl      = (const float*)d_in[4];
    const float* bl      = (const float*)d_in[5];
    const float* Wih     = (const float*)d_in[6];
    const float* Whh     = (const float*)d_in[7];
    const float* bih     = (const float*)d_in[8];
    const float* bhh     = (const float*)d_in[9];
    const float* Wout    = (const float*)d_in[10];
    const float* bout    = (const float*)d_in[11];

    short* wsS  = (short*)d_ws;
    float* bsum = (float*)((char*)d_ws + BSUM_BYTE_OFF);

    prep_kernel<<<280, 256, 0, stream>>>(Wl, Wih, Whh, bih, bhh, wsS, bsum);
    rnn_kernel<<<256, 512, 0, stream>>>(dense, sparse, lengths, emb, bl, Wout, bout,
                                        wsS, bsum, (float*)d_out);
}

// Round 8
// 1205.297 us; speedup vs baseline: 5.1740x; 1.1408x over previous
//
#include <hip/hip_runtime.h>
#include <math.h>

// ---------------------------------------------------------------------------
// RNN_48558900248904. Round 8: weights global->VGPR via 3-slot rolling
// register pipeline (load chunk kk+2 while computing kk), fully unrolled.
// __launch_bounds__(512,1): hipcc's 2nd arg acts like CUDA min-blocks/CU, so
// (512,2) capped VGPR at 128 (R4/R5 spills); (512,1) unlocks the 256 bin.
// No LDS round-trip for weights (R7's ring paid ~12K cyc/step LDS read BW on
// top of the same L2 traffic). LDS keeps activations only (83KB).
// ---------------------------------------------------------------------------

typedef __attribute__((ext_vector_type(8))) short bf16x8;   // 8 bf16 (4 VGPRs)
typedef __attribute__((ext_vector_type(4))) short s16x4;    // 8B store
typedef __attribute__((ext_vector_type(4))) float f32x4;

#define MFMA(a, b, c) __builtin_amdgcn_mfma_f32_16x16x32_bf16((a), (b), (c), 0, 0, 0)

#define T_  200

// ws layout (shorts)
#define WLP_OFF   0                       // Wl packed: ((mt*5+kk)*64+lane)*8
#define WIHP_OFF  40960                   // 4 mats x 65536
#define WHHP_OFF  (40960 + 262144)
#define BSUM_BYTE_OFF ((40960 + 262144 + 262144) * 2)   // then [2][2][256] f32

// LDS layout (shorts)
#define XCS 168
#define HS  264
#define SM_XCAT 0                         // [32][168] = 5376
#define SM_XPJ  5376                      // [32][264] = 8448 each
#define SM_H0   (SM_XPJ + 8448)
#define SM_H1A  (SM_H0 + 8448)
#define SM_H1B  (SM_H1A + 8448)
#define SM_BIAS (SM_H1B + 8448)          // 1280 f32 = 2560 shorts
#define SM_TOT  (SM_BIAS + 2560)         // 41984 shorts = 83968 B

__device__ __forceinline__ short f2bf(float f) {
    unsigned u = __float_as_uint(f);
    u += 0x7fffu + ((u >> 16) & 1u);      // RNE
    return (short)(u >> 16);
}
__device__ __forceinline__ float bf2f(short s) {
    return __uint_as_float(((unsigned)(unsigned short)s) << 16);
}
__device__ __forceinline__ float tanh_fast(float x) {
    float e = __builtin_amdgcn_exp2f(x * 2.88539008f);
    return 1.0f - 2.0f * __builtin_amdgcn_rcpf(e + 1.0f);
}

// ---------------------------------------------------------------------------
__global__ void prep_kernel(const float* __restrict__ Wl,
                            const float* __restrict__ Wih,
                            const float* __restrict__ Whh,
                            const float* __restrict__ bih,
                            const float* __restrict__ bhh,
                            short* __restrict__ wsS,
                            float* __restrict__ bsum) {
    int tid = blockIdx.x * 256 + threadIdx.x;
    if (tid < 5120) {                       // Wl pack (K padded 136 -> 160)
        int mt = tid / 320, rem = tid % 320;
        int kk = rem / 64, lane = rem % 64;
        int o = mt * 16 + (lane & 15);
        int kb = kk * 32 + (lane >> 4) * 8;
        short* dst = wsS + WLP_OFF + tid * 8;
#pragma unroll
        for (int e = 0; e < 8; e++) {
            int k = kb + e;
            dst[e] = f2bf((k < 136) ? Wl[o * 136 + k] : 0.0f);
        }
    } else if (tid < 5120 + 32768) {        // Wih pack
        int jj = tid - 5120;
        int mat = jj / 8192, rem = jj % 8192;
        int lane = rem & 63, kk = (rem >> 6) & 7, mt = rem >> 9;
        int o = mt * 16 + (lane & 15);
        int kb = kk * 32 + (lane >> 4) * 8;
        const float* src = Wih + (mat * 256 + o) * 256;
        short* dst = wsS + WIHP_OFF + mat * 65536 + rem * 8;
#pragma unroll
        for (int e = 0; e < 8; e++) dst[e] = f2bf(src[kb + e]);
    } else if (tid < 5120 + 65536) {        // Whh pack
        int jj = tid - 37888;
        int mat = jj / 8192, rem = jj % 8192;
        int lane = rem & 63, kk = (rem >> 6) & 7, mt = rem >> 9;
        int o = mt * 16 + (lane & 15);
        int kb = kk * 32 + (lane >> 4) * 8;
        const float* src = Whh + (mat * 256 + o) * 256;
        short* dst = wsS + WHHP_OFF + mat * 65536 + rem * 8;
#pragma unroll
        for (int e = 0; e < 8; e++) dst[e] = f2bf(src[kb + e]);
    } else if (tid < 5120 + 65536 + 1024) { // bsum = bih + bhh
        int j = tid - 70656;
        bsum[j] = bih[j] + bhh[j];
    }
}

// ---------------------------------------------------------------------------
struct GReg { f32x4 e0, e1, dv; };

__device__ __forceinline__ void gather_load(GReg& g, const float* __restrict__ dense,
                                            const int* __restrict__ sparse,
                                            const float* __restrict__ emb,
                                            int b0, int tt, int tid) {
    int gs = tid >> 4, gf = (tid >> 2) & 3, gq = tid & 3;
    int ix = sparse[(b0 + gs) * (T_ * 4) + tt * 4 + gf];
    const float* ep = emb + gf * 32000 + ix * 32 + gq * 8;
    g.e0 = *(const f32x4*)ep;
    g.e1 = *(const f32x4*)(ep + 4);
    if (tid < 64)
        g.dv = *(const f32x4*)(dense + (b0 + (tid >> 1)) * (T_ * 8) + tt * 8 + (tid & 1) * 4);
}
__device__ __forceinline__ void gather_commit(const GReg& g, short* __restrict__ buf, int tid) {
    int gs = tid >> 4, gf = (tid >> 2) & 3, gq = tid & 3;
    s16x4 w0, w1;
#pragma unroll
    for (int r = 0; r < 4; r++) { w0[r] = f2bf(g.e0[r]); w1[r] = f2bf(g.e1[r]); }
    int off = gs * XCS + 8 + gf * 32 + gq * 8;
    *(s16x4*)(buf + off) = w0;
    *(s16x4*)(buf + off + 4) = w1;
    if (tid < 64) {
        s16x4 wd;
#pragma unroll
        for (int r = 0; r < 4; r++) wd[r] = f2bf(g.dv[r]);
        *(s16x4*)(buf + (tid >> 1) * XCS + (tid & 1) * 4) = wd;
    }
}

// xproj = relu(Wl x xcat + bl): 3-slot rolling register pipeline on Wl
__device__ __forceinline__ void phaseA(const short* __restrict__ xcat,
                                       short* __restrict__ xpj,
                                       const short* __restrict__ Wlp,
                                       const float* __restrict__ blS,
                                       int lane, int lrow, int lgrp, int wid) {
    bf16x8 wl[3][2];
#pragma unroll
    for (int j = 0; j < 2; j++) {
        wl[j][0] = *(const bf16x8*)(Wlp + (((wid * 2 + 0) * 5 + j) * 64 + lane) * 8);
        wl[j][1] = *(const bf16x8*)(Wlp + (((wid * 2 + 1) * 5 + j) * 64 + lane) * 8);
    }
    f32x4 xacc[2][2];
#pragma unroll
    for (int mt = 0; mt < 2; mt++) {
        f32x4 bi = *(const f32x4*)(blS + wid * 32 + mt * 16 + lgrp * 4);
        xacc[mt][0] = bi; xacc[mt][1] = bi;
    }
#pragma unroll
    for (int kk = 0; kk < 5; kk++) {
        const int cur = kk % 3;
        if (kk < 3) {
            const int nxt = (kk + 2) % 3;
            wl[nxt][0] = *(const bf16x8*)(Wlp + (((wid * 2 + 0) * 5 + kk + 2) * 64 + lane) * 8);
            wl[nxt][1] = *(const bf16x8*)(Wlp + (((wid * 2 + 1) * 5 + kk + 2) * 64 + lane) * 8);
        }
        bf16x8 bxf[2];
#pragma unroll
        for (int nt = 0; nt < 2; nt++)
            bxf[nt] = *(const bf16x8*)(xcat + (nt * 16 + lrow) * XCS + kk * 32 + lgrp * 8);
#pragma unroll
        for (int mt = 0; mt < 2; mt++)
#pragma unroll
            for (int nt = 0; nt < 2; nt++) xacc[mt][nt] = MFMA(wl[cur][mt], bxf[nt], xacc[mt][nt]);
    }
#pragma unroll
    for (int mt = 0; mt < 2; mt++) {
        int o0 = wid * 32 + mt * 16 + lgrp * 4;
#pragma unroll
        for (int nt = 0; nt < 2; nt++) {
            s16x4 w;
#pragma unroll
            for (int r = 0; r < 4; r++) w[r] = f2bf(fmaxf(xacc[mt][nt][r], 0.0f));
            *(s16x4*)(xpj + (nt * 16 + lrow) * HS + o0) = w;
        }
    }
}

// ---------------------------------------------------------------------------
__global__ __launch_bounds__(512, 1) void rnn_kernel(
    const float* __restrict__ dense, const int* __restrict__ sparse,
    const int* __restrict__ lengths, const float* __restrict__ emb,
    const float* __restrict__ bl, const float* __restrict__ Wout,
    const float* __restrict__ bout, const short* __restrict__ wsS,
    const float* __restrict__ bsum, float* __restrict__ out) {
    __shared__ alignas(16) short sm[SM_TOT];
    short* xcat = sm + SM_XCAT;
    short* xpj  = sm + SM_XPJ;
    short* h0p  = sm + SM_H0;
    short* h1a  = sm + SM_H1A;
    short* h1b  = sm + SM_H1B;
    float* blS  = (float*)(sm + SM_BIAS);

    const int tid  = threadIdx.x;
    const int wid  = tid >> 6;
    const int lane = tid & 63;
    const int lrow = lane & 15;
    const int lgrp = lane >> 4;
    const int b0   = blockIdx.x * 32;
    const short* Wlp = wsS + WLP_OFF;

    for (int i = tid; i < SM_BIAS; i += 512) sm[i] = 0;
    for (int i = tid; i < 1280; i += 512)
        blS[i] = (i < 256) ? bl[i] : bsum[i - 256];

    const int len0 = lengths[b0 + lrow];
    const int len1 = lengths[b0 + 16 + lrow];

    __syncthreads();
    { GReg g0; gather_load(g0, dense, sparse, emb, b0, 0, tid); gather_commit(g0, xcat, tid); }
    __syncthreads();
    phaseA(xcat, xpj, Wlp, blS, lane, lrow, lgrp, wid);   // xproj(0)

    bf16x8 hreg0[2][8];             // h0(-1) = 0
#pragma unroll
    for (int nt = 0; nt < 2; nt++)
#pragma unroll
        for (int kk = 0; kk < 8; kk++) {
            bf16x8 z;
#pragma unroll
            for (int e = 0; e < 8; e++) z[e] = 0;
            hreg0[nt][kk] = z;
        }
    __syncthreads();               // xpj(0) visible

    for (int t = 0; t < T_; t++) {
        const int p = t & 1;
        const bool hasNext = (t + 1 < T_);
        const short* Aih1 = wsS + WIHP_OFF + p * 65536;
        const short* Ahh1 = wsS + WHHP_OFF + p * 65536;
        const short* Aih2 = wsS + WIHP_OFF + (2 + p) * 65536;
        const short* Ahh2 = wsS + WHHP_OFF + (2 + p) * 65536;

        GReg g;
        if (hasNext) gather_load(g, dense, sparse, emb, b0, t + 1, tid);

        // ================= P1: layer0(t) =================
        {
            bf16x8 wa[3][4];   // rolling chunks: [slot][ih0,ih1,hh0,hh1]
#pragma unroll
            for (int j = 0; j < 2; j++) {
                wa[j][0] = *(const bf16x8*)(Aih1 + (((wid * 2 + 0) * 8 + j) * 64 + lane) * 8);
                wa[j][1] = *(const bf16x8*)(Aih1 + (((wid * 2 + 1) * 8 + j) * 64 + lane) * 8);
                wa[j][2] = *(const bf16x8*)(Ahh1 + (((wid * 2 + 0) * 8 + j) * 64 + lane) * 8);
                wa[j][3] = *(const bf16x8*)(Ahh1 + (((wid * 2 + 1) * 8 + j) * 64 + lane) * 8);
            }
            f32x4 acc[2][2];
#pragma unroll
            for (int mt = 0; mt < 2; mt++) {
                f32x4 bi = *(const f32x4*)(blS + 256 + p * 256 + wid * 32 + mt * 16 + lgrp * 4);
                acc[mt][0] = bi; acc[mt][1] = bi;
            }
#pragma unroll
            for (int kk = 0; kk < 8; kk++) {
                const int cur = kk % 3;
                if (kk < 6) {
                    const int nxt = (kk + 2) % 3;
                    wa[nxt][0] = *(const bf16x8*)(Aih1 + (((wid * 2 + 0) * 8 + kk + 2) * 64 + lane) * 8);
                    wa[nxt][1] = *(const bf16x8*)(Aih1 + (((wid * 2 + 1) * 8 + kk + 2) * 64 + lane) * 8);
                    wa[nxt][2] = *(const bf16x8*)(Ahh1 + (((wid * 2 + 0) * 8 + kk + 2) * 64 + lane) * 8);
                    wa[nxt][3] = *(const bf16x8*)(Ahh1 + (((wid * 2 + 1) * 8 + kk + 2) * 64 + lane) * 8);
                }
                bf16x8 bxf[2];
#pragma unroll
                for (int nt = 0; nt < 2; nt++)
                    bxf[nt] = *(const bf16x8*)(xpj + (nt * 16 + lrow) * HS + kk * 32 + lgrp * 8);
#pragma unroll
                for (int mt = 0; mt < 2; mt++)
#pragma unroll
                    for (int nt = 0; nt < 2; nt++) {
                        acc[mt][nt] = MFMA(wa[cur][mt], bxf[nt], acc[mt][nt]);
                        acc[mt][nt] = MFMA(wa[cur][2 + mt], hreg0[nt][kk], acc[mt][nt]);
                    }
            }
#pragma unroll
            for (int mt = 0; mt < 2; mt++) {        // in-place predicated h0 write
                int o0 = wid * 32 + mt * 16 + lgrp * 4;
#pragma unroll
                for (int nt = 0; nt < 2; nt++) {
                    s16x4 w;
#pragma unroll
                    for (int r = 0; r < 4; r++) w[r] = f2bf(tanh_fast(acc[mt][nt][r]));
                    int len = nt ? len1 : len0;
                    if (t < len)
                        *(s16x4*)(h0p + (nt * 16 + lrow) * HS + o0) = w;
                }
            }
        }
        if (hasNext) gather_commit(g, xcat, tid);
        __syncthreads();   // h0(t), xcat(t+1) visible

        // ================= P2: layer1(t) + xproj(t+1) =================
        {
            const short* h1r = p ? h1b : h1a;
            short* h1w = p ? h1a : h1b;

            bf16x8 wa[3][4];
#pragma unroll
            for (int j = 0; j < 2; j++) {
                wa[j][0] = *(const bf16x8*)(Aih2 + (((wid * 2 + 0) * 8 + j) * 64 + lane) * 8);
                wa[j][1] = *(const bf16x8*)(Aih2 + (((wid * 2 + 1) * 8 + j) * 64 + lane) * 8);
                wa[j][2] = *(const bf16x8*)(Ahh2 + (((wid * 2 + 0) * 8 + j) * 64 + lane) * 8);
                wa[j][3] = *(const bf16x8*)(Ahh2 + (((wid * 2 + 1) * 8 + j) * 64 + lane) * 8);
            }
            f32x4 acc[2][2];
#pragma unroll
            for (int mt = 0; mt < 2; mt++) {
                f32x4 bi = *(const f32x4*)(blS + 256 + (2 + p) * 256 + wid * 32 + mt * 16 + lgrp * 4);
                acc[mt][0] = bi; acc[mt][1] = bi;
            }
#pragma unroll
            for (int kk = 0; kk < 8; kk++) {
                const int cur = kk % 3;
                if (kk < 6) {
                    const int nxt = (kk + 2) % 3;
                    wa[nxt][0] = *(const bf16x8*)(Aih2 + (((wid * 2 + 0) * 8 + kk + 2) * 64 + lane) * 8);
                    wa[nxt][1] = *(const bf16x8*)(Aih2 + (((wid * 2 + 1) * 8 + kk + 2) * 64 + lane) * 8);
                    wa[nxt][2] = *(const bf16x8*)(Ahh2 + (((wid * 2 + 0) * 8 + kk + 2) * 64 + lane) * 8);
                    wa[nxt][3] = *(const bf16x8*)(Ahh2 + (((wid * 2 + 1) * 8 + kk + 2) * 64 + lane) * 8);
                }
                bf16x8 bhf[2];
#pragma unroll
                for (int nt = 0; nt < 2; nt++) {    // fresh h0: ih operand + next P1 hh
                    hreg0[nt][kk] = *(const bf16x8*)(h0p + (nt * 16 + lrow) * HS + kk * 32 + lgrp * 8);
                    bhf[nt] = *(const bf16x8*)(h1r + (nt * 16 + lrow) * HS + kk * 32 + lgrp * 8);
                }
#pragma unroll
                for (int mt = 0; mt < 2; mt++)
#pragma unroll
                    for (int nt = 0; nt < 2; nt++) {
                        acc[mt][nt] = MFMA(wa[cur][mt], hreg0[nt][kk], acc[mt][nt]);
                        acc[mt][nt] = MFMA(wa[cur][2 + mt], bhf[nt], acc[mt][nt]);
                    }
            }

            if (hasNext)   // independent GEMM: interleaves with layer1 above
                phaseA(xcat, xpj, Wlp, blS, lane, lrow, lgrp, wid);

            // h1 ping-pong select-freeze
#pragma unroll
            for (int mt = 0; mt < 2; mt++) {
                int o0 = wid * 32 + mt * 16 + lgrp * 4;
#pragma unroll
                for (int nt = 0; nt < 2; nt++) {
                    int roff = (nt * 16 + lrow) * HS + o0;
                    s16x4 oldv = *(const s16x4*)(h1r + roff);
                    s16x4 w;
#pragma unroll
                    for (int r = 0; r < 4; r++) w[r] = f2bf(tanh_fast(acc[mt][nt][r]));
                    int len = nt ? len1 : len0;
                    *(s16x4*)(h1w + roff) = (t < len) ? w : oldv;
                }
            }
        }
        __syncthreads();   // h1(t), xpj(t+1) visible
    }

    // ---- epilogue: out = sigmoid(h1 . Wout + bout); final h1 = h1a (T even)
    float* red = (float*)(sm + SM_XPJ);
    if (tid < 256) {
        int s = tid >> 3, part = tid & 7;
        const short* hr = h1a + s * HS + part * 32;
        float sum = 0.0f;
#pragma unroll
        for (int k = 0; k < 32; k++) sum += bf2f(hr[k]) * Wout[part * 32 + k];
        red[s * 8 + part] = sum;
    }
    __syncthreads();
    if (tid < 32) {
        float x = bout[0];
#pragma unroll
        for (int i = 0; i < 8; i++) x += red[tid * 8 + i];
        float e = __builtin_amdgcn_exp2f(x * 1.44269504f);
        out[b0 + tid] = 1.0f - __builtin_amdgcn_rcpf(1.0f + e);
    }
}

// ---------------------------------------------------------------------------
extern "C" void kernel_launch(void* const* d_in, const int* in_sizes, int n_in,
                              void* d_out, int out_size, void* d_ws, size_t ws_size,
                              hipStream_t stream) {
    const float* dense   = (const float*)d_in[0];
    const int*   sparse  = (const int*)d_in[1];
    const int*   lengths = (const int*)d_in[2];
    const float* emb     = (const float*)d_in[3];
    const float* Wl      = (const float*)d_in[4];
    const float* bl      = (const float*)d_in[5];
    const float* Wih     = (const float*)d_in[6];
    const float* Whh     = (const float*)d_in[7];
    const float* bih     = (const float*)d_in[8];
    const float* bhh     = (const float*)d_in[9];
    const float* Wout    = (const float*)d_in[10];
    const float* bout    = (const float*)d_in[11];

    short* wsS  = (short*)d_ws;
    float* bsum = (float*)((char*)d_ws + BSUM_BYTE_OFF);

    prep_kernel<<<280, 256, 0, stream>>>(Wl, Wih, Whh, bih, bhh, wsS, bsum);
    rnn_kernel<<<256, 512, 0, stream>>>(dense, sparse, lengths, emb, bl, Wout, bout,
                                        wsS, bsum, (float*)d_out);
}